// Round 7
// baseline (699.988 us; speedup 1.0000x reference)
//
#include <hip/hip_runtime.h>
#include <hip/hip_bf16.h>

#define B_    1024
#define C_    896
#define N_    49
#define NN    2401
#define HD    128
#define NH    7
#define CQK   1792      // q,k rows of W (V never used)
#define KTOP  2160      // int(2401*0.9)
#define SCALE 0.08838834764831845f  // 128^-0.5
#define MG    50176     // 1024*49 token rows

typedef unsigned short ushort_t;
typedef unsigned int u32;
typedef short bf16x8 __attribute__((ext_vector_type(8)));
typedef float f32x4  __attribute__((ext_vector_type(4)));

__device__ __forceinline__ ushort_t f2bf(float f) {
  u32 u = __builtin_bit_cast(u32, f);
  u += 0x7FFFu + ((u >> 16) & 1u);          // RNE
  return (ushort_t)(u >> 16);
}

__device__ __forceinline__ void gload16(const ushort_t* g, ushort_t* l) {
  __builtin_amdgcn_global_load_lds((const __attribute__((address_space(1))) u32*)g,
                                   (__attribute__((address_space(3))) u32*)l, 16, 0, 0);
}

#define BAR()   __builtin_amdgcn_s_barrier()
#define LGKM0() do { asm volatile("s_waitcnt lgkmcnt(0)" ::: "memory"); \
                     __builtin_amdgcn_sched_barrier(0); } while (0)
#define VMC(n)  do { asm volatile("s_waitcnt vmcnt(" #n ")" ::: "memory"); \
                     __builtin_amdgcn_sched_barrier(0); } while (0)

// ---------------- kernel 1: W -> bf16, head-permuted ----------------
// out row r (r in [0,1792)): h = r>>8, sub = r&255;
// src = (sub<128) ? h*128+sub : 896 + h*128 + (sub-128)
__global__ void k_convW(const float* __restrict__ W, ushort_t* __restrict__ Wbf) {
  int i = blockIdx.x * 256 + threadIdx.x;          // quad index
  if (i >= CQK * C_ / 4) return;
  int r = i / (C_ / 4);
  int c4 = (i - r * (C_ / 4)) * 4;
  int h = r >> 8, sub = r & 255;
  int src = (sub < 128) ? (h * HD + sub) : (C_ + h * HD + (sub - 128));
  const float* wp = W + (size_t)src * C_ + c4;
  ushort_t o[4];
#pragma unroll
  for (int u = 0; u < 4; ++u) o[u] = f2bf(wp[u]);
  *(unsigned long long*)(Wbf + (size_t)r * C_ + c4) = *(unsigned long long*)o;
}

// ---------------- kernel 2: transpose x -> tokens bf16 [MG][896] ----------------
__global__ __launch_bounds__(256) void k_tr(const float* __restrict__ x,
                                            ushort_t* __restrict__ tokens) {
  __shared__ ushort_t T2[49][76];
  const int bid = blockIdx.x;
  const int bl  = bid / 14;            // batch
  const int cg  = bid % 14;            // c-group (64 channels)
  const float* xb = x + (size_t)bl * (C_ * N_) + (size_t)cg * 64 * N_;
  for (int idx = threadIdx.x; idx < 784; idx += 256) {   // 64*49/4 float4s
    float4 f = ((const float4*)xb)[idx];
    int e0 = idx * 4;
#pragma unroll
    for (int u = 0; u < 4; ++u) {
      int e = e0 + u;
      int ci = e / 49, n = e - ci * 49;
      float v = (u == 0) ? f.x : (u == 1) ? f.y : (u == 2) ? f.z : f.w;
      T2[n][ci] = f2bf(v);
    }
  }
  __syncthreads();
  ushort_t* tb = tokens + (size_t)(bl * 49) * C_ + cg * 64;
  for (int idx = threadIdx.x; idx < 49 * 8; idx += 256) {
    int n = idx >> 3, ch = idx & 7;
    *(bf16x8*)(tb + (size_t)n * C_ + ch * 8) = *(const bf16x8*)&T2[n][ch * 8];
  }
}

// ---------------- kernel 3: fused GEMM + logits + softmax + atomic-min ----------------
// Block = (m-chunk: 5 batches = 245 rows pad 256) x (head: 256 cols [Q_h|K_h]).
// 8-phase K-loop identical to R6. Epilogue: acc -> LDS [256][264], then waves 0-4
// compute per-batch logits/softmax and atomicMin into fused (u32-ordered positive f32).
#define QKL_STR 264                       // 528 B/row: b128-aligned, 33 slots -> conflict-free
#define GATTN_LDS (256 * QKL_STR * 2)     // 135168 > 131072 staging: union

__global__ __launch_bounds__(512, 2) void k_gattn(const ushort_t* __restrict__ tokens,
                                                  const ushort_t* __restrict__ Wbf,
                                                  u32* __restrict__ fusedg) {
  extern __shared__ ushort_t gsm[];
  ushort_t* sA = gsm;            // 32768 els (2 slots x 2 half x 128 x 64)
  ushort_t* sB = gsm + 32768;
  ushort_t* QKL = gsm;           // epilogue reuse: [256][264]

  // bijective XCD-chunk swizzle (m204)
  const int nwg = gridDim.x;
  const int q8 = nwg >> 3, r8 = nwg & 7;
  const int xcd = blockIdx.x & 7, idx8 = blockIdx.x >> 3;
  const int tile = (xcd < r8 ? xcd * (q8 + 1) : r8 * (q8 + 1) + (xcd - r8) * q8) + idx8;

  const int chunk = tile / 7, head = tile - chunk * 7;
  const int m0 = chunk * 245;            // 5 whole batches
  const int n0 = head * 256;             // head panel in permuted Wbf

  const int t = threadIdx.x;
  const int w = t >> 6, l = t & 63;
  const int lrow = l & 15, hi = l >> 4;
  const int wm = w & 1, wn = w >> 1;     // wn 0..3

  const int srow = t >> 3;                          // 0..63
  const int scol = 8 * ((t & 7) ^ (srow & 7));      // pre-swizzled source col
  ushort_t* ldsA = sA + t * 8;
  ushort_t* ldsB = sB + t * 8;
  const ushort_t* wSrc = Wbf + (size_t)(n0 + srow) * C_ + scol;

  const int ph0 = 8 * (hi ^ (lrow & 7));
  const int ph1 = 8 * ((4 + hi) ^ (lrow & 7));
  const ushort_t* aBase = sA + wm * 8192 + lrow * 64;
  const ushort_t* bBase = sB + (wn >> 1) * 8192 + ((wn & 1) * 64 + lrow) * 64;

  f32x4 acc[8][4];
#pragma unroll
  for (int m = 0; m < 8; ++m)
#pragma unroll
    for (int n = 0; n < 4; ++n) acc[m][n] = (f32x4){0.f, 0.f, 0.f, 0.f};

  bf16x8 a[4][2], b[4][2];

  auto STA = [&](int kt, int half) {
    const int slot = kt & 1;
#pragma unroll
    for (int j = 0; j < 2; ++j) {
      int gr = m0 + half * 128 + j * 64 + srow;
      if (gr >= MG) gr = MG - 1;
      gload16(tokens + (size_t)gr * C_ + kt * 64 + scol,
              ldsA + slot * 16384 + half * 8192 + j * 4096);
    }
  };
  auto STB = [&](int kt, int half) {
    const int slot = kt & 1;
#pragma unroll
    for (int j = 0; j < 2; ++j)
      gload16(wSrc + (size_t)(half * 128 + j * 64) * C_ + kt * 64,
              ldsB + slot * 16384 + half * 8192 + j * 4096);
  };
  auto LDA = [&](int slot, int mq) {
#pragma unroll
    for (int mm = 0; mm < 4; ++mm) {
      const ushort_t* p = aBase + slot * 16384 + (mq * 4 + mm) * 1024;
      a[mm][0] = *(const bf16x8*)(p + ph0);
      a[mm][1] = *(const bf16x8*)(p + ph1);
    }
  };
  auto LDB = [&](int slot, int np) {
#pragma unroll
    for (int nn = 0; nn < 2; ++nn) {
      const ushort_t* p = bBase + slot * 16384 + (np * 2 + nn) * 1024;
      b[np * 2 + nn][0] = *(const bf16x8*)(p + ph0);
      b[np * 2 + nn][1] = *(const bf16x8*)(p + ph1);
    }
  };
  auto MM = [&](int mq, int np) {
    __builtin_amdgcn_s_setprio(1);
#pragma unroll
    for (int mm = 0; mm < 4; ++mm)
#pragma unroll
      for (int nn = 0; nn < 2; ++nn) {
        const int n = np * 2 + nn;
#pragma unroll
        for (int kh = 0; kh < 2; ++kh)
          acc[mq * 4 + mm][n] =
              __builtin_amdgcn_mfma_f32_16x16x32_bf16(a[mm][kh], b[n][kh],
                                                      acc[mq * 4 + mm][n], 0, 0, 0);
      }
    __builtin_amdgcn_s_setprio(0);
  };

  // prologue
  STA(0, 0); STA(0, 1); STB(0, 0); STB(0, 1);
  STB(1, 0); STB(1, 1); STA(1, 0);
  VMC(6);
  BAR();

#pragma unroll 1
  for (int it = 0; it < 7; ++it) {
    const int k1 = 2 * it + 1, k2 = 2 * it + 2, k3 = 2 * it + 3;
    const bool st = (it < 6);
    // P1
    LDA(0, 0); LDB(0, 0);
    STA(k1, 1);
    BAR(); LGKM0(); MM(0, 0); BAR();
    // P2
    LDB(0, 1);
    BAR(); LGKM0(); MM(0, 1); BAR();
    // P3
    LDA(0, 1);
    if (st) STB(k2, 0);
    BAR(); LGKM0(); MM(1, 1); BAR();
    // P4
    if (st) STB(k2, 1);
    BAR(); MM(1, 0);
    if (st) { VMC(4); } else { VMC(0); }
    BAR();
    // P5
    LDA(1, 0); LDB(1, 0);
    if (st) STA(k2, 0);
    BAR(); LGKM0(); MM(0, 0); BAR();
    // P6
    LDB(1, 1);
    if (st) STA(k2, 1);
    BAR(); LGKM0(); MM(0, 1); BAR();
    // P7
    LDA(1, 1);
    if (st) STB(k3, 0);
    BAR(); LGKM0(); MM(1, 1); BAR();
    // P8
    if (st) { STB(k3, 1); STA(k3, 0); }
    BAR(); MM(1, 0);
    if (st) { VMC(6); } else { VMC(0); }
    BAR();
  }

  // ---- epilogue: acc -> LDS [256][264], SCALE folded into Q cols (<128) ----
#pragma unroll
  for (int m = 0; m < 8; ++m) {
#pragma unroll
    for (int n = 0; n < 4; ++n) {
      int col = wn * 64 + n * 16 + lrow;
      float sc = (col < 128) ? SCALE : 1.0f;
#pragma unroll
      for (int r = 0; r < 4; ++r) {
        int row = wm * 128 + m * 16 + hi * 4 + r;
        QKL[row * QKL_STR + col] = f2bf(acc[m][n][r] * sc);
      }
    }
  }
  __syncthreads();

  // ---- waves 0-4: per-batch logits + softmax + atomicMin ----
  if (w < 5) {
    const int gb = chunk * 5 + w;
    if (gb < B_) {
      const int rb = w * 49;
      const f32x4 z4 = {0.f, 0.f, 0.f, 0.f};
      int qr[4], kr[4];
#pragma unroll
      for (int i = 0; i < 4; ++i) {
        int r = i * 16 + lrow; if (r > 48) r = 48;
        qr[i] = rb + r; kr[i] = rb + r;
      }
      const int lk = hi * 8;
      f32x4 acc2[4][4];
#pragma unroll
      for (int qt = 0; qt < 4; ++qt)
#pragma unroll
        for (int kt = 0; kt < 4; ++kt) acc2[qt][kt] = z4;
#pragma unroll
      for (int e = 0; e < 4; ++e) {
        bf16x8 kf[4], qf[4];
#pragma unroll
        for (int kt = 0; kt < 4; ++kt)
          kf[kt] = *(const bf16x8*)(QKL + kr[kt] * QKL_STR + 128 + e * 32 + lk);
#pragma unroll
        for (int qt = 0; qt < 4; ++qt)
          qf[qt] = *(const bf16x8*)(QKL + qr[qt] * QKL_STR + e * 32 + lk);
#pragma unroll
        for (int qt = 0; qt < 4; ++qt)
#pragma unroll
          for (int kt = 0; kt < 4; ++kt)
            acc2[qt][kt] = __builtin_amdgcn_mfma_f32_16x16x32_bf16(kf[kt], qf[qt],
                                                                   acc2[qt][kt], 0, 0, 0);
      }
      u32* fb = fusedg + (size_t)gb * NN;
#pragma unroll
      for (int qt = 0; qt < 4; ++qt) {
        float mx = -1e30f;
#pragma unroll
        for (int kt = 0; kt < 4; ++kt)
#pragma unroll
          for (int r = 0; r < 4; ++r) {
            int k = kt * 16 + hi * 4 + r;
            if (k < N_) mx = fmaxf(mx, acc2[qt][kt][r]);
          }
        mx = fmaxf(mx, __shfl_xor(mx, 16));
        mx = fmaxf(mx, __shfl_xor(mx, 32));
        float ev[16];
        float sum = 0.f;
#pragma unroll
        for (int kt = 0; kt < 4; ++kt)
#pragma unroll
          for (int r = 0; r < 4; ++r) {
            int k = kt * 16 + hi * 4 + r;
            float e = (k < N_) ? __expf(acc2[qt][kt][r] - mx) : 0.f;
            ev[kt * 4 + r] = e;
            sum += e;
          }
        sum += __shfl_xor(sum, 16);
        sum += __shfl_xor(sum, 32);
        float rs = 1.0f / sum;
        int q = qt * 16 + lrow;
        if (q < N_) {
#pragma unroll
          for (int kt = 0; kt < 4; ++kt)
#pragma unroll
            for (int r = 0; r < 4; ++r) {
              int k = kt * 16 + hi * 4 + r;
              if (k < N_) {
                float p = ev[kt * 4 + r] * rs;
                atomicMin(&fb[q * N_ + k], __builtin_bit_cast(u32, p));
              }
            }
        }
      }
    }
  }
}

// ---------------- kernel 4: select (bottom-2160 mask union) + rollout ----------------
__global__ void k_selroll(const float* __restrict__ fusedg, u32* __restrict__ gmask,
                          float* __restrict__ att) {
  __shared__ u32 v[NN];
  __shared__ u32 lmask[76];
  __shared__ int cnt;
  const int b = blockIdx.x, t = threadIdx.x;
  for (int p = t; p < NN; p += 256)
    v[p] = __builtin_bit_cast(u32, fusedg[(size_t)b * NN + p]);
  for (int p = t; p < 76; p += 256) lmask[p] = 0u;
  __syncthreads();
  u32 u = 0;
  for (int bit = 30; bit >= 0; --bit) {
    u32 cand = u | (1u << bit);
    if (t == 0) cnt = 0;
    __syncthreads();
    int c = 0;
    for (int p = t; p < NN; p += 256) c += (v[p] < cand) ? 1 : 0;
    atomicAdd(&cnt, c);
    __syncthreads();
    if (cnt < KTOP) u = cand;
    __syncthreads();
  }
  for (int p = t; p < NN; p += 256)
    if (p != 0 && v[p] <= u) atomicOr(&lmask[p >> 5], 1u << (p & 31));
  __syncthreads();
  for (int p = t; p < 76; p += 256)
    if (lmask[p]) atomicOr(&gmask[p], lmask[p]);
  if (t < N_) {
    float rs = 0.f, cs = 0.f;
    for (int m = 0; m < N_; ++m) {
      rs += __builtin_bit_cast(float, v[t * N_ + m]);
      cs += __builtin_bit_cast(float, v[m * N_ + t]);
    }
    att[b * N_ + t] = (cs + 1.0f) / (49.0f * (rs + 1.0f));
  }
}

// ---------------- kernel 5: batch-0 fixup ----------------
__global__ void k_fix0(const float* __restrict__ fusedg, const u32* __restrict__ gmask,
                       float* __restrict__ att) {
  __shared__ float fl[NN];
  const int t = threadIdx.x;
  for (int p = t; p < NN; p += 256) {
    float vv = fusedg[p];
    if ((gmask[p >> 5] >> (p & 31)) & 1u) vv = 0.f;
    fl[p] = vv;
  }
  __syncthreads();
  if (t < N_) {
    float rs = 0.f, cs = 0.f;
    for (int m = 0; m < N_; ++m) { rs += fl[t * N_ + m]; cs += fl[m * N_ + t]; }
    att[t] = (cs + 1.0f) / (49.0f * (rs + 1.0f));
  }
}

// ---------------- kernel 6: rx = x * (1 + att[b,n]) ----------------
__global__ void k_rx(const float* __restrict__ x, const float* __restrict__ att,
                     float* __restrict__ out) {
  const int total4 = B_ * C_ * N_ / 4;
  for (int g = blockIdx.x * 256 + threadIdx.x; g < total4; g += gridDim.x * 256) {
    u32 e0 = (u32)g * 4u;
    u32 b = e0 / (u32)(C_ * N_);
    u32 r = e0 - b * (u32)(C_ * N_);
    u32 n = r % (u32)N_;
    const float4 xv = ((const float4*)x)[g];
    const float* ab = att + b * N_;
    float a0 = ab[n];
    u32 n1 = n + 1;  if (n1 == N_) n1 = 0;  float a1 = ab[n1];
    u32 n2 = n1 + 1; if (n2 == N_) n2 = 0;  float a2 = ab[n2];
    u32 n3 = n2 + 1; if (n3 == N_) n3 = 0;  float a3 = ab[n3];
    float4 o;
    o.x = xv.x * (1.f + a0); o.y = xv.y * (1.f + a1);
    o.z = xv.z * (1.f + a2); o.w = xv.w * (1.f + a3);
    ((float4*)out)[g] = o;
  }
}

extern "C" void kernel_launch(void* const* d_in, const int* in_sizes, int n_in,
                              void* d_out, int out_size, void* d_ws, size_t ws_size,
                              hipStream_t stream) {
  const float* x = (const float*)d_in[0];
  const float* W = (const float*)d_in[1];
  float* out = (float*)d_out;
  char* ws = (char*)d_ws;

  float*    fused = (float*)ws;                         // 9,834,496 B
  float*    att   = (float*)(ws + 9834496);             //   200,704 B
  ushort_t* Wbf   = (ushort_t*)(ws + 9834496 + 200704); // 3,211,264 B
  u32*      gmask = (u32*)(ws + 9834496 + 200704 + 3211264);
  ushort_t* tokens = (ushort_t*)d_out;   // scratch; d_out fully rewritten by k_rx

  hipMemsetAsync(gmask, 0, 76 * sizeof(u32), stream);
  hipMemsetAsync(fused, 0x7F, 9834496, stream);   // +3.39e38 in every f32
  k_convW<<<(CQK * C_ / 4 + 255) / 256, 256, 0, stream>>>(W, Wbf);
  k_tr<<<B_ * 14, 256, 0, stream>>>(x, tokens);

  hipFuncSetAttribute((const void*)k_gattn, hipFuncAttributeMaxDynamicSharedMemorySize,
                      GATTN_LDS);
  k_gattn<<<205 * 7, 512, GATTN_LDS, stream>>>(tokens, Wbf, (u32*)fused);

  k_selroll<<<B_, 256, 0, stream>>>(fused, gmask, att);
  k_fix0<<<1, 256, 0, stream>>>(fused, gmask, att);
  k_rx<<<2048, 256, 0, stream>>>(x, att, out);
}

// Round 8
// 368.615 us; speedup vs baseline: 1.8990x; 1.8990x over previous
//
#include <hip/hip_runtime.h>
#include <hip/hip_bf16.h>

#define B_    1024
#define C_    896
#define N_    49
#define NN    2401
#define HD    128
#define NH    7
#define CQK   1792      // q,k rows of W (V never used)
#define KTOP  2160      // int(2401*0.9)
#define SCALE 0.08838834764831845f  // 128^-0.5

typedef unsigned short ushort_t;
typedef unsigned int u32;
typedef short bf16x8 __attribute__((ext_vector_type(8)));
typedef float f32x4  __attribute__((ext_vector_type(4)));

__device__ __forceinline__ ushort_t f2bf(float f) {
  u32 u = __builtin_bit_cast(u32, f);
  u += 0x7FFFu + ((u >> 16) & 1u);          // RNE
  return (ushort_t)(u >> 16);
}

__device__ __forceinline__ void gload16(const ushort_t* g, ushort_t* l) {
  __builtin_amdgcn_global_load_lds((const __attribute__((address_space(1))) u32*)g,
                                   (__attribute__((address_space(3))) u32*)l, 16, 0, 0);
}

#define BAR()   __builtin_amdgcn_s_barrier()
#define LGKM0() do { asm volatile("s_waitcnt lgkmcnt(0)" ::: "memory"); \
                     __builtin_amdgcn_sched_barrier(0); } while (0)
#define VMC(n)  do { asm volatile("s_waitcnt vmcnt(" #n ")" ::: "memory"); \
                     __builtin_amdgcn_sched_barrier(0); } while (0)

// ---------------- kernel 1: W (first 1792 rows) -> bf16 ----------------
__global__ void k_convW(const float* __restrict__ W, ushort_t* __restrict__ Wbf) {
  int i = blockIdx.x * 256 + threadIdx.x;          // quad index
  if (i >= CQK * C_ / 4) return;
  const float* wp = W + (size_t)i * 4;
  ushort_t o[4];
#pragma unroll
  for (int u = 0; u < 4; ++u) o[u] = f2bf(wp[u]);
  *(unsigned long long*)(Wbf + (size_t)i * 4) = *(unsigned long long*)o;
}

// ---------------- kernel 2: transpose x -> tokens bf16 [MG][896] ----------------
__global__ __launch_bounds__(256) void k_tr(const float* __restrict__ x,
                                            ushort_t* __restrict__ tokens,
                                            int boff) {
  __shared__ ushort_t T2[49][76];
  const int bid = blockIdx.x;
  const int bl  = bid / 14;            // local batch
  const int cg  = bid % 14;            // c-group (64 channels)
  const float* xb = x + (size_t)(boff + bl) * (C_ * N_) + (size_t)cg * 64 * N_;
  for (int idx = threadIdx.x; idx < 784; idx += 256) {   // 64*49/4 float4s
    float4 f = ((const float4*)xb)[idx];
    int e0 = idx * 4;
#pragma unroll
    for (int u = 0; u < 4; ++u) {
      int e = e0 + u;
      int ci = e / 49, n = e - ci * 49;
      float v = (u == 0) ? f.x : (u == 1) ? f.y : (u == 2) ? f.z : f.w;
      T2[n][ci] = f2bf(v);
    }
  }
  __syncthreads();
  ushort_t* tb = tokens + (size_t)(bl * 49) * C_ + cg * 64;
  for (int idx = threadIdx.x; idx < 49 * 8; idx += 256) {
    int n = idx >> 3, ch = idx & 7;
    *(bf16x8*)(tb + (size_t)n * C_ + ch * 8) = *(const bf16x8*)&T2[n][ch * 8];
  }
}

// ---------------- kernel 3: GEMM QK = tokens * Wbf^T, merged 4-phase ----------------
// 256x256 tile, BK=64, 8 waves, 2-slot dbuf (128 KB). 8 barriers/iter (vs 16),
// vmcnt(6) twice per iter (never 0 mid-loop). Swizzle as R6 (verified, 0 conflicts).
#define GEMM_LDS 131072

__global__ __launch_bounds__(512, 2) void k_gemm(const ushort_t* __restrict__ tokens,
                                                 const ushort_t* __restrict__ Wbf,
                                                 ushort_t* __restrict__ QK,
                                                 int MG) {
  extern __shared__ ushort_t gsm[];
  ushort_t* sA = gsm;            // 32768 els (2 slots x 2 half x 128 x 64)
  ushort_t* sB = gsm + 32768;

  // bijective XCD-chunk swizzle (m204)
  const int nwg = gridDim.x;
  const int q8 = nwg >> 3, r8 = nwg & 7;
  const int xcd = blockIdx.x & 7, idx8 = blockIdx.x >> 3;
  const int tile = (xcd < r8 ? xcd * (q8 + 1) : r8 * (q8 + 1) + (xcd - r8) * q8) + idx8;

  const int mt = tile / 7, nt = tile - mt * 7;
  const int m0 = mt * 256, n0 = nt * 256;

  const int t = threadIdx.x;
  const int w = t >> 6, l = t & 63;
  const int lrow = l & 15, hi = l >> 4;
  const int wm = w & 1, wn = w >> 1;   // wn 0..3

  // stage-side: thread t covers row (t>>3) of a 64-row j-unit, 16B piece (t&7)
  const int srow = t >> 3;                          // 0..63
  const int scol = 8 * ((t & 7) ^ (srow & 7));      // pre-swizzled source col (els)
  ushort_t* ldsA = sA + t * 8;
  ushort_t* ldsB = sB + t * 8;
  const ushort_t* wSrc = Wbf + (size_t)(n0 + srow) * C_ + scol;

  // frag-side: phys 16B piece = (kh*4+hi) ^ (row&7); row%8 == lrow%8
  const int ph0 = 8 * (hi ^ (lrow & 7));
  const int ph1 = 8 * ((4 + hi) ^ (lrow & 7));
  const ushort_t* aBase = sA + wm * 8192 + lrow * 64;
  const ushort_t* bBase = sB + (wn >> 1) * 8192 + ((wn & 1) * 64 + lrow) * 64;

  f32x4 acc[8][4];
#pragma unroll
  for (int m = 0; m < 8; ++m)
#pragma unroll
    for (int n = 0; n < 4; ++n) acc[m][n] = (f32x4){0.f, 0.f, 0.f, 0.f};

  bf16x8 a[4][2], b[4][2];

  // stage A j-unit (64 rows) of BOTH m-halves for tile kt: 2 gloads
  auto STAJ = [&](int kt, int j) {
    const int slot = kt & 1;
#pragma unroll
    for (int half = 0; half < 2; ++half) {
      int gr = m0 + half * 128 + j * 64 + srow;
      if (gr >= MG) gr = MG - 1;
      gload16(tokens + (size_t)gr * C_ + kt * 64 + scol,
              ldsA + slot * 16384 + half * 8192 + j * 4096);
    }
  };
  auto STB = [&](int kt, int half) {
    const int slot = kt & 1;
#pragma unroll
    for (int j = 0; j < 2; ++j)
      gload16(wSrc + (size_t)(half * 128 + j * 64) * C_ + kt * 64,
              ldsB + slot * 16384 + half * 8192 + j * 4096);
  };
  auto LDA = [&](int slot, int mq) {
#pragma unroll
    for (int mm = 0; mm < 4; ++mm) {
      const ushort_t* p = aBase + slot * 16384 + (mq * 4 + mm) * 1024;
      a[mm][0] = *(const bf16x8*)(p + ph0);
      a[mm][1] = *(const bf16x8*)(p + ph1);
    }
  };
  auto LDB = [&](int slot, int np) {
#pragma unroll
    for (int nn = 0; nn < 2; ++nn) {
      const ushort_t* p = bBase + slot * 16384 + (np * 2 + nn) * 1024;
      b[np * 2 + nn][0] = *(const bf16x8*)(p + ph0);
      b[np * 2 + nn][1] = *(const bf16x8*)(p + ph1);
    }
  };
  auto MM = [&](int mq, int np) {
#pragma unroll
    for (int mm = 0; mm < 4; ++mm)
#pragma unroll
      for (int nn = 0; nn < 2; ++nn) {
        const int n = np * 2 + nn;
#pragma unroll
        for (int kh = 0; kh < 2; ++kh)
          acc[mq * 4 + mm][n] =
              __builtin_amdgcn_mfma_f32_16x16x32_bf16(a[mm][kh], b[n][kh],
                                                      acc[mq * 4 + mm][n], 0, 0, 0);
      }
  };

  // prologue: tile0 fully (8 gloads) + tile1 B + A-j0 (6) -> 14 in flight
  STAJ(0, 0); STAJ(0, 1); STB(0, 0); STB(0, 1);
  STB(1, 0); STB(1, 1); STAJ(1, 0);
  VMC(6);
  BAR();

#pragma unroll 1
  for (int it = 0; it < 7; ++it) {
    const int c1 = 2 * it + 1, c2 = 2 * it + 2, c3 = 2 * it + 3;
    const bool st = (it < 6);
    // P1: reads slot0 {A-mq0, B-all}; stage c1 A-j1
    LDA(0, 0); LDB(0, 0); LDB(0, 1);
    STAJ(c1, 1);
    BAR(); LGKM0();
    __builtin_amdgcn_s_setprio(1); MM(0, 0); MM(0, 1); __builtin_amdgcn_s_setprio(0);
    BAR();
    // P2: reads slot0 A-mq1; stage c2 {B x2, A-j0}
    LDA(0, 1);
    if (st) { STB(c2, 0); STB(c2, 1); STAJ(c2, 0); }
    BAR(); LGKM0();
    __builtin_amdgcn_s_setprio(1); MM(1, 0); MM(1, 1); __builtin_amdgcn_s_setprio(0);
    if (st) { VMC(6); } else { VMC(0); }
    BAR();
    // P3: reads slot1 {A-mq0, B-all}; stage c2 A-j1
    LDA(1, 0); LDB(1, 0); LDB(1, 1);
    if (st) STAJ(c2, 1);
    BAR(); LGKM0();
    __builtin_amdgcn_s_setprio(1); MM(0, 0); MM(0, 1); __builtin_amdgcn_s_setprio(0);
    BAR();
    // P4: reads slot1 A-mq1; stage c3 {B x2, A-j0}
    LDA(1, 1);
    if (st) { STB(c3, 0); STB(c3, 1); STAJ(c3, 0); }
    BAR(); LGKM0();
    __builtin_amdgcn_s_setprio(1); MM(1, 0); MM(1, 1); __builtin_amdgcn_s_setprio(0);
    if (st) { VMC(6); } else { VMC(0); }
    BAR();
  }

  // epilogue: D col=lane&15, row=(lane>>4)*4+r; fold SCALE into Q cols (<896)
#pragma unroll
  for (int m = 0; m < 8; ++m) {
#pragma unroll
    for (int n = 0; n < 4; ++n) {
      int gcol = n0 + wn * 64 + n * 16 + lrow;
      float sc = (gcol < C_) ? SCALE : 1.0f;
#pragma unroll
      for (int r = 0; r < 4; ++r) {
        int grow = m0 + wm * 128 + m * 16 + hi * 4 + r;
        if (grow < MG)
          QK[(size_t)grow * CQK + gcol] = f2bf(acc[m][n][r] * sc);
      }
    }
  }
}

// ---------------- kernel 4: logits+softmax+min+select+rollout, one WAVE per batch ----------------
__global__ __launch_bounds__(256) void k_attn2(const ushort_t* __restrict__ QK,
                                               float* __restrict__ att,
                                               u32* __restrict__ gmask,
                                               float* __restrict__ fused0,
                                               int boff) {
  __shared__ u32 lmask[76];
  const int tid  = threadIdx.x;
  const int wid  = tid >> 6;
  const int lane = tid & 63;
  const int lrow = lane & 15;
  const int hi   = lane >> 4;
  const int lk   = hi * 8;
  const int bloc = blockIdx.x * 4 + wid;
  const int bg   = boff + bloc;
  const f32x4 z4 = {0.f, 0.f, 0.f, 0.f};

  for (int p = tid; p < 76; p += 256) lmask[p] = 0u;
  __syncthreads();

  const ushort_t* Qb = QK + (size_t)bloc * 49 * CQK;
  const ushort_t* Kb = Qb + C_;

  int rr[4];
#pragma unroll
  for (int i = 0; i < 4; ++i) {
    int r = i * 16 + lrow; if (r > 48) r = 48;
    rr[i] = r;
  }

  float fu[4][16];

  for (int h = 0; h < NH; ++h) {
    f32x4 acc[4][4];   // [qt][kt]
#pragma unroll
    for (int qt = 0; qt < 4; ++qt)
#pragma unroll
      for (int kt = 0; kt < 4; ++kt) acc[qt][kt] = z4;

#pragma unroll
    for (int e = 0; e < 4; ++e) {
      bf16x8 kf[4], qf[4];
#pragma unroll
      for (int kt = 0; kt < 4; ++kt)
        kf[kt] = *(const bf16x8*)(Kb + (size_t)rr[kt] * CQK + h * HD + e * 32 + lk);
#pragma unroll
      for (int qt = 0; qt < 4; ++qt)
        qf[qt] = *(const bf16x8*)(Qb + (size_t)rr[qt] * CQK + h * HD + e * 32 + lk);
#pragma unroll
      for (int qt = 0; qt < 4; ++qt)
#pragma unroll
        for (int kt = 0; kt < 4; ++kt)
          acc[qt][kt] = __builtin_amdgcn_mfma_f32_16x16x32_bf16(kf[kt], qf[qt],
                                                                acc[qt][kt], 0, 0, 0);
    }

#pragma unroll
    for (int qt = 0; qt < 4; ++qt) {
      float mx = -1e30f;
#pragma unroll
      for (int kt = 0; kt < 4; ++kt)
#pragma unroll
        for (int r = 0; r < 4; ++r) {
          int k = kt * 16 + hi * 4 + r;
          if (k < N_) mx = fmaxf(mx, acc[qt][kt][r]);
        }
      mx = fmaxf(mx, __shfl_xor(mx, 16));
      mx = fmaxf(mx, __shfl_xor(mx, 32));
      float ev[16];
      float sum = 0.f;
#pragma unroll
      for (int kt = 0; kt < 4; ++kt)
#pragma unroll
        for (int r = 0; r < 4; ++r) {
          int k = kt * 16 + hi * 4 + r;
          float e = (k < N_) ? __expf(acc[qt][kt][r] - mx) : 0.f;
          ev[kt * 4 + r] = e;
          sum += e;
        }
      sum += __shfl_xor(sum, 16);
      sum += __shfl_xor(sum, 32);
      float rs = 1.0f / sum;
#pragma unroll
      for (int i = 0; i < 16; ++i) {
        float p = ev[i] * rs;
        fu[qt][i] = (h == 0) ? p : fminf(fu[qt][i], p);
      }
    }
  }

  // ---- bits with validity pad (+INF never selected/counted) ----
  u32 vb[4][16];
#pragma unroll
  for (int qt = 0; qt < 4; ++qt) {
    int q = qt * 16 + lrow;
#pragma unroll
    for (int i = 0; i < 16; ++i) {
      int k = (i >> 2) * 16 + hi * 4 + (i & 3);
      vb[qt][i] = (q < N_ && k < N_) ? __builtin_bit_cast(u32, fu[qt][i]) : 0x7F800000u;
    }
  }

  // ---- in-wave binary search: largest u with count(v < u) < KTOP ----
  u32 thr = 0;
  for (int bit = 29; bit >= 0; --bit) {
    u32 cand = thr | (1u << bit);
    int c = 0;
#pragma unroll
    for (int qt = 0; qt < 4; ++qt)
#pragma unroll
      for (int i = 0; i < 16; ++i) c += (vb[qt][i] < cand) ? 1 : 0;
    c += __shfl_xor(c, 1);  c += __shfl_xor(c, 2);  c += __shfl_xor(c, 4);
    c += __shfl_xor(c, 8);  c += __shfl_xor(c, 16); c += __shfl_xor(c, 32);
    if (c < KTOP) thr = cand;
  }

  // ---- membership -> block LDS mask ----
#pragma unroll
  for (int qt = 0; qt < 4; ++qt) {
    int q = qt * 16 + lrow;
#pragma unroll
    for (int i = 0; i < 16; ++i) {
      int k = (i >> 2) * 16 + hi * 4 + (i & 3);
      int p = q * N_ + k;
      if (q < N_ && k < N_ && p != 0 && vb[qt][i] <= thr)
        atomicOr(&lmask[p >> 5], 1u << (p & 31));
    }
  }

  // ---- rollout: rs over k (in-lane + hi), cs over q (in-lane qt + lrow) ----
  float rsv[4];
#pragma unroll
  for (int qt = 0; qt < 4; ++qt) {
    int q = qt * 16 + lrow;
    float s = 0.f;
#pragma unroll
    for (int i = 0; i < 16; ++i) {
      int k = (i >> 2) * 16 + hi * 4 + (i & 3);
      s += (q < N_ && k < N_) ? fu[qt][i] : 0.f;
    }
    s += __shfl_xor(s, 16); s += __shfl_xor(s, 32);
    rsv[qt] = s;
  }
  float csv[16];
#pragma unroll
  for (int i = 0; i < 16; ++i) {
    int k = (i >> 2) * 16 + hi * 4 + (i & 3);
    float s = 0.f;
#pragma unroll
    for (int qt = 0; qt < 4; ++qt) {
      int q = qt * 16 + lrow;
      s += (q < N_ && k < N_) ? fu[qt][i] : 0.f;
    }
    s += __shfl_xor(s, 1); s += __shfl_xor(s, 2);
    s += __shfl_xor(s, 4); s += __shfl_xor(s, 8);
    csv[i] = s;
  }
  // att[bg][t]: t = kt*16 + hi*4 + r; rs fetched from lane lrow = t%16
#pragma unroll
  for (int kt = 0; kt < 4; ++kt)
#pragma unroll
    for (int r = 0; r < 4; ++r) {
      int tt = kt * 16 + hi * 4 + r;
      float rv = __shfl(rsv[kt], hi * 4 + r);
      if (lrow == 0 && tt < N_)
        att[(size_t)bg * N_ + tt] = (csv[kt * 4 + r] + 1.0f) / (49.0f * (rv + 1.0f));
    }

  // ---- batch 0: spill fused values for the fixup kernel ----
  if (bg == 0) {
#pragma unroll
    for (int qt = 0; qt < 4; ++qt) {
      int q = qt * 16 + lrow;
#pragma unroll
      for (int i = 0; i < 16; ++i) {
        int k = (i >> 2) * 16 + hi * 4 + (i & 3);
        if (q < N_ && k < N_) fused0[q * N_ + k] = fu[qt][i];
      }
    }
  }

  __syncthreads();
  for (int p = tid; p < 76; p += 256)
    if (lmask[p]) atomicOr(&gmask[p], lmask[p]);
}

// ---------------- kernel 5: batch-0 fixup: apply union mask, redo rollout ----------------
__global__ void k_fix0(const float* __restrict__ fused0, const u32* __restrict__ gmask,
                       float* __restrict__ att) {
  __shared__ float fl[NN];
  const int t = threadIdx.x;
  for (int p = t; p < NN; p += 256) {
    float vv = fused0[p];
    if ((gmask[p >> 5] >> (p & 31)) & 1u) vv = 0.f;
    fl[p] = vv;
  }
  __syncthreads();
  if (t < N_) {
    float rs = 0.f, cs = 0.f;
    for (int m = 0; m < N_; ++m) { rs += fl[t * N_ + m]; cs += fl[m * N_ + t]; }
    att[t] = (cs + 1.0f) / (49.0f * (rs + 1.0f));
  }
}

// ---------------- kernel 6: rx = x * (1 + att[b,n]) ----------------
__global__ void k_rx(const float* __restrict__ x, const float* __restrict__ att,
                     float* __restrict__ out) {
  const int total4 = B_ * C_ * N_ / 4;
  for (int g = blockIdx.x * 256 + threadIdx.x; g < total4; g += gridDim.x * 256) {
    u32 e0 = (u32)g * 4u;
    u32 b = e0 / (u32)(C_ * N_);
    u32 r = e0 - b * (u32)(C_ * N_);
    u32 n = r % (u32)N_;
    const float4 xv = ((const float4*)x)[g];
    const float* ab = att + b * N_;
    float a0 = ab[n];
    u32 n1 = n + 1;  if (n1 == N_) n1 = 0;  float a1 = ab[n1];
    u32 n2 = n1 + 1; if (n2 == N_) n2 = 0;  float a2 = ab[n2];
    u32 n3 = n2 + 1; if (n3 == N_) n3 = 0;  float a3 = ab[n3];
    float4 o;
    o.x = xv.x * (1.f + a0); o.y = xv.y * (1.f + a1);
    o.z = xv.z * (1.f + a2); o.w = xv.w * (1.f + a3);
    ((float4*)out)[g] = o;
  }
}

extern "C" void kernel_launch(void* const* d_in, const int* in_sizes, int n_in,
                              void* d_out, int out_size, void* d_ws, size_t ws_size,
                              hipStream_t stream) {
  const float* x = (const float*)d_in[0];
  const float* W = (const float*)d_in[1];
  float* out = (float*)d_out;
  char* ws = (char*)d_ws;

  // group size G (batches per pass): multiples of 256 so MG % 256 == 0
  const size_t fixed = 200704 /*att*/ + 3211264 /*Wbf*/ + 1024 /*gmask*/ + 9632 /*fused0*/;
  int G = 256;
  const int cands[3] = {1024, 512, 256};
  for (int i = 0; i < 3; ++i) {
    if (fixed + (size_t)cands[i] * 49 * CQK * 2 <= ws_size) { G = cands[i]; break; }
  }

  const size_t qkbytes = (size_t)G * 49 * CQK * 2;
  ushort_t* QKg    = (ushort_t*)ws;
  float*    att    = (float*)(ws + qkbytes);
  ushort_t* Wbf    = (ushort_t*)(ws + qkbytes + 200704);
  u32*      gmask  = (u32*)(ws + qkbytes + 200704 + 3211264);
  float*    fused0 = (float*)(ws + qkbytes + 200704 + 3211264 + 1024);
  ushort_t* tokens = (ushort_t*)d_out;   // scratch; d_out fully rewritten by k_rx

  hipMemsetAsync(gmask, 0, 76 * sizeof(u32), stream);
  k_convW<<<(CQK * C_ / 4 + 255) / 256, 256, 0, stream>>>(W, Wbf);

  hipFuncSetAttribute((const void*)k_gemm, hipFuncAttributeMaxDynamicSharedMemorySize, GEMM_LDS);

  const int ngroups = B_ / G;
  for (int g = 0; g < ngroups; ++g) {
    const int boff = g * G;
    const int MG = G * 49;
    const int mtc = MG / 256;
    k_tr<<<G * 14, 256, 0, stream>>>(x, tokens, boff);
    k_gemm<<<mtc * 7, 512, GEMM_LDS, stream>>>(tokens, Wbf, QKg, MG);
    k_attn2<<<G / 4, 256, 0, stream>>>(QKg, att, gmask, fused0, boff);
  }

  k_fix0<<<1, 256, 0, stream>>>(fused0, gmask, att);
  k_rx<<<4096, 256, 0, stream>>>(x, att, out);
}